// Round 4
// baseline (441.771 us; speedup 1.0000x reference)
//
#include <hip/hip_runtime.h>
#include <hip/hip_bf16.h>

// GCN_71451075936314 on gfx950.
// R13: R12 design + workspace shrunk to proven bound. R12's container fault
//      attributed to workspace OOB (91.4MB vs 65.4MB proven). Aliasing:
//      featB dead after ggemm -> hTB at ws+0; sage reads float feature
//      directly (same f2bf rounding); h1nB/aggB alias dead Gp; gout aliases
//      dead hTB. Peak 64.8MB.
// R12: (a) G-precompute: gates_x = feat@Wih^T + bias computed ONCE per node
//          (8.5x reuse) by dense GEMM, stored bf16 gate-packed
//          G'[n][hcol*4+gate]. Recurrence keeps only h-part MFMA.
//      (b) 1024-thr/64-node lstm, transposed-C MFMA with packed vrows
//          (vrow = hcol_local*4+gate): lane's f32x4 = all 4 gates of ONE
//          cell; Whh pinned = 32 VGPR/thread -> ~120 regs ->
//          launch_bounds(1024,4) -> 16 waves/CU (2x R11's occupancy).

#define NN     50000
#define HIDD   128
#define MAXD   16
#define NGRAPH 50
#define NCLSS  10
#define GRUH   32

typedef __attribute__((ext_vector_type(8))) short s16x8;    // 8 bf16 (4 VGPRs)
typedef __attribute__((ext_vector_type(4))) float f32x4;
typedef __hip_bfloat16 bf16;

#define MFMA16(a,b,c)  __builtin_amdgcn_mfma_f32_16x16x32_bf16((a),(b),(c),0,0,0)

__device__ __forceinline__ float bf2f(bf16 x) { return __bfloat162float(x); }
__device__ __forceinline__ bf16  f2bf(float x) { return __float2bfloat16(x); }
__device__ __forceinline__ s16x8 ldfrag(const bf16* p) { return *(const s16x8*)p; }

__device__ __forceinline__ s16x8 ldfrag_f32(const float* p) {
  const float4 a = *(const float4*)p;
  const float4 b = *(const float4*)(p + 4);
  union { s16x8 v; bf16 h[8]; } r;
  r.h[0] = f2bf(a.x); r.h[1] = f2bf(a.y); r.h[2] = f2bf(a.z); r.h[3] = f2bf(a.w);
  r.h[4] = f2bf(b.x); r.h[5] = f2bf(b.y); r.h[6] = f2bf(b.z); r.h[7] = f2bf(b.w);
  return r.v;
}

__device__ __forceinline__ float sigf(float x) {
  return __builtin_amdgcn_rcpf(1.0f + __expf(-x));
}
__device__ __forceinline__ float tanhf_(float x) {
  return 1.0f - 2.0f * __builtin_amdgcn_rcpf(1.0f + __expf(2.0f * x));
}

__device__ __forceinline__ unsigned packbf2(float a, float b) {
  union { bf16 h; unsigned short u; } x, y;
  x.h = f2bf(a); y.h = f2bf(b);
  return (unsigned)x.u | ((unsigned)y.u << 16);
}
__device__ __forceinline__ float lo2f(unsigned u) { return __uint_as_float(u << 16); }
__device__ __forceinline__ float hi2f(unsigned u) { return __uint_as_float(u & 0xffff0000u); }

// barrier that drains LDS ops only — global loads stay in flight
__device__ __forceinline__ void lgkm_barrier() {
  asm volatile("s_waitcnt lgkmcnt(0)\n\ts_barrier" ::: "memory");
}

// ---------------- prep: bf16 casts + weight transposes + bias fold ----------------
__global__ void prep_kernel(const float* __restrict__ feat, const float* __restrict__ Wih,
                            const float* __restrict__ Whh, const float* __restrict__ bih,
                            const float* __restrict__ bhh, const float* __restrict__ Wself,
                            const float* __restrict__ Wneigh, const float* __restrict__ Wgc,
                            const float* __restrict__ Wgru,
                            bf16* featB, bf16* WihB, bf16* WhhB, bf16* WsT, bf16* WnT,
                            bf16* WgT, bf16* WgruB, float* biasS) {
  const int nf = NN * HIDD;
  const int total = nf + 2 * 65536 + 3 * 16384 + 12288 + 512;
  int stride = gridDim.x * blockDim.x;
  for (int idx = blockIdx.x * blockDim.x + threadIdx.x; idx < total; idx += stride) {
    if (idx < nf) { featB[idx] = f2bf(feat[idx]); continue; }
    int j = idx - nf;
    if (j < 65536) { WihB[j] = f2bf(Wih[j]); continue; }
    j -= 65536;
    if (j < 65536) { WhhB[j] = f2bf(Whh[j]); continue; }
    j -= 65536;
    if (j < 16384) { int c = j >> 7, k = j & 127; WsT[j] = f2bf(Wself[k * HIDD + c]); continue; }
    j -= 16384;
    if (j < 16384) { int c = j >> 7, k = j & 127; WnT[j] = f2bf(Wneigh[k * HIDD + c]); continue; }
    j -= 16384;
    if (j < 16384) { int c = j >> 7, k = j & 127; WgT[j] = f2bf(Wgc[k * HIDD + c]); continue; }
    j -= 16384;
    if (j < 12288) { WgruB[j] = f2bf(Wgru[j]); continue; }
    j -= 12288;
    biasS[j] = bih[j] + bhh[j];
  }
}

// ---------------- counting sort by degree (DESCENDING): LDS hist ----------------
__global__ __launch_bounds__(256) void hist_kernel(const int* __restrict__ deg, int* hist) {
  __shared__ int lh[17];
  const int tid = threadIdx.x;
  if (tid < 17) lh[tid] = 0;
  __syncthreads();
  const int i = blockIdx.x * 256 + tid;
  if (i < NN) atomicAdd(&lh[deg[i]], 1);
  __syncthreads();
  if (tid < 17 && lh[tid]) atomicAdd(&hist[tid], lh[tid]);
}

__global__ __launch_bounds__(256) void scatter_kernel(const int* __restrict__ deg,
                                                      const int* __restrict__ hist,
                                                      int* __restrict__ resv,
                                                      int* __restrict__ perm) {
  __shared__ int lh[17], lbase[17], lpos[17];
  const int tid = threadIdx.x;
  if (tid < 17) { lh[tid] = 0; lpos[tid] = 0; }
  __syncthreads();
  const int i = blockIdx.x * 256 + tid;
  const int d = (i < NN) ? deg[i] : -1;
  if (d >= 0) atomicAdd(&lh[d], 1);
  __syncthreads();
  if (tid < 17) {
    int pre = 0;
    for (int k = tid + 1; k < 17; ++k) pre += hist[k];   // descending: larger degs first
    lbase[tid] = pre + (lh[tid] ? atomicAdd(&resv[tid], lh[tid]) : 0);
  }
  __syncthreads();
  if (d >= 0) {
    const int p = lbase[d] + atomicAdd(&lpos[d], 1);
    perm[p] = i;
  }
}

// ---------------- G-GEMM: G'[n][hcol*4+gate] = feat[n] @ Wih^T + bias ----------------
// Transposed-C MFMA with packed vrows (vrow = hl*4 + gate): lane's f32x4 =
// 4 gates of one hcol -> one 8B bf16x4 store, gate-packed for lstm gathers.
__global__ __launch_bounds__(256) void ggemm_kernel(const bf16* __restrict__ featB,
                                                    const bf16* __restrict__ WihB,
                                                    const float* __restrict__ biasS,
                                                    bf16* __restrict__ Gp) {
  const int lane = threadIdx.x & 63, wave = threadIdx.x >> 6;
  const int l15 = lane & 15, quad = lane >> 4;
  const int nb = blockIdx.x * 64;

  // x B-frags: 64 rows of featB, 16 per l15-slot x 4 nt, k-chunk by quad
  s16x8 Bx[4][4];
#pragma unroll
  for (int nt = 0; nt < 4; ++nt) {
    int arow = nb + nt * 16 + l15; if (arow >= NN) arow = NN - 1;
#pragma unroll
    for (int kt = 0; kt < 4; ++kt)
      Bx[nt][kt] = ldfrag(featB + (size_t)arow * HIDD + kt * 32 + quad * 8);
  }

  for (int hg = wave * 8; hg < wave * 8 + 8; ++hg) {
    // A-frags: Wih packed vrows: row = (l15&3)*128 + hg*4 + (l15>>2)
    const int wr = (l15 & 3) * HIDD + hg * 4 + (l15 >> 2);
    s16x8 Aw[4];
#pragma unroll
    for (int kt = 0; kt < 4; ++kt)
      Aw[kt] = ldfrag(WihB + (size_t)wr * HIDD + kt * 32 + quad * 8);
    const int hcol = hg * 4 + quad;
    float b0 = biasS[0 * HIDD + hcol], b1 = biasS[1 * HIDD + hcol];
    float b2 = biasS[2 * HIDD + hcol], b3 = biasS[3 * HIDD + hcol];
#pragma unroll
    for (int nt = 0; nt < 4; ++nt) {
      f32x4 acc = {0.f, 0.f, 0.f, 0.f};
#pragma unroll
      for (int kt = 0; kt < 4; ++kt)
        acc = MFMA16(Aw[kt], Bx[nt][kt], acc);
      const int node = nb + nt * 16 + l15;
      if (node < NN) {
        unsigned u0 = packbf2(acc[0] + b0, acc[1] + b1);
        unsigned u1 = packbf2(acc[2] + b2, acc[3] + b3);
        *(uint2*)(Gp + (size_t)node * 512 + hcol * 4) = make_uint2(u0, u1);
      }
    }
  }
}

// ---------------- LSTM recurrence: 1024 thr / 16 waves / 64 nodes ----------------
// h-part only (x-gates gathered from G'). Transposed-C MFMA, packed vrows:
// wave w owns hcols [w*8, w*8+8) as 2 gt-tiles of 4 hcols x 4 gates.
// Lane (l15,quad) acc[gt][nt] f32x4 = gates i,f,g,o of cell
// (node nt*16+l15, hcol w*8+gt*4+quad). Whh pinned 32 VGPR. 16 waves/CU.
__global__ __launch_bounds__(1024, 4) void lstm_kernel(const bf16* __restrict__ Gp,
                                                       const bf16* __restrict__ WhhB,
                                                       const int* __restrict__ nbr_idx,
                                                       const int* __restrict__ deg,
                                                       const int* __restrict__ perm,
                                                       bf16* __restrict__ hTB) {
  __shared__ __align__(16) bf16 Hs[2][64 * 128];  // 32KB: h dbuf, oct-xor swizzled
  __shared__ int nbr_s[16 * 64];                  // [t][row]
  __shared__ int nodes_s[64];
  __shared__ int degs_s[64];

  const int tid = threadIdx.x;
  const int lane = tid & 63, w = tid >> 6;        // w = hcol-block 0..15
  const int l15 = lane & 15, quad = lane >> 4;
  const int base = blockIdx.x * 64;

  if (tid < 64) {
    const int gi = base + tid;
    const int nd = (gi < NN) ? perm[gi] : -1;
    nodes_s[tid] = nd;
    degs_s[tid] = (nd >= 0) ? deg[nd] : 0;
  }
  __syncthreads();
  {
    const int row = tid & 63, t = tid >> 6;       // exactly one entry per thread
    const int nd = nodes_s[row];
    nbr_s[t * 64 + row] = (nd >= 0) ? nbr_idx[nd * MAXD + t] : 0;
  }

  // pinned Whh packed frags: vrow v=l15 -> Whh row (v&3)*128 + w*8 + gt*4 + (v>>2)
  s16x8 Bh[2][4];
#pragma unroll
  for (int gt = 0; gt < 2; ++gt) {
    const int wr = (l15 & 3) * HIDD + w * 8 + gt * 4 + (l15 >> 2);
#pragma unroll
    for (int kt = 0; kt < 4; ++kt) {
      Bh[gt][kt] = ldfrag(WhhB + (size_t)wr * HIDD + kt * 32 + quad * 8);
      asm volatile("" : "+v"(Bh[gt][kt]));
    }
  }

  __syncthreads();                                // nbr_s visible
  const int maxdeg = degs_s[0];                   // descending sort -> block max

  int mydeg[4];
#pragma unroll
  for (int nt = 0; nt < 4; ++nt) mydeg[nt] = degs_s[nt * 16 + l15];

  // per-thread G' element offsets (col base = (w*8+gt*4+quad)*4)
  const int gofs0 = (w * 8 + 0 * 4 + quad) * 4;
  const int gofs1 = (w * 8 + 1 * 4 + quad) * 4;

  float cst[2][4] = {{0.f, 0.f, 0.f, 0.f}, {0.f, 0.f, 0.f, 0.f}};
  float hprev[2][4] = {{0.f, 0.f, 0.f, 0.f}, {0.f, 0.f, 0.f, 0.f}};

  for (int t = 0; t < maxdeg; ++t) {
    const int cur = t & 1, nxt = cur ^ 1;

    // gather x-gates for this step (consumed in cell; latency hidden by MFMA)
    uint2 gx[2][4];
#pragma unroll
    for (int nt = 0; nt < 4; ++nt) {
      const int nb1 = nbr_s[t * 64 + nt * 16 + l15];
      const bf16* gr = Gp + (size_t)nb1 * 512;
      gx[0][nt] = *(const uint2*)(gr + gofs0);
      gx[1][nt] = *(const uint2*)(gr + gofs1);
    }

    f32x4 acc[2][4];
#pragma unroll
    for (int gt = 0; gt < 2; ++gt)
#pragma unroll
      for (int nt = 0; nt < 4; ++nt) acc[gt][nt] = (f32x4){0.f, 0.f, 0.f, 0.f};

    // h-part: gates += Whh_packed @ h^T  (skip at t=0: h0 = 0)
    if (t > 0) {
#pragma unroll
      for (int kt = 0; kt < 4; ++kt) {
#pragma unroll
        for (int nt = 0; nt < 4; ++nt) {
          const int row = nt * 16 + l15;
          const s16x8 ah = ldfrag(Hs[cur] + row * 128 + (((kt * 4 + quad) ^ l15) * 8));
#pragma unroll
          for (int gt = 0; gt < 2; ++gt)
            acc[gt][nt] = MFMA16(Bh[gt][kt], ah, acc[gt][nt]);
        }
      }
    }

    // elementwise cell: lane's f32x4 = all 4 gates of one cell
#pragma unroll
    for (int gt = 0; gt < 2; ++gt) {
      const int col = w * 8 + gt * 4 + quad;
#pragma unroll
      for (int nt = 0; nt < 4; ++nt) {
        const int row = nt * 16 + l15;
        const uint2 g = gx[gt][nt];
        const float g_i = acc[gt][nt][0] + lo2f(g.x);
        const float g_f = acc[gt][nt][1] + hi2f(g.x);
        const float g_g = acc[gt][nt][2] + lo2f(g.y);
        const float g_o = acc[gt][nt][3] + hi2f(g.y);
        const float iv = sigf(g_i), fv = sigf(g_f);
        const float gv = tanhf_(g_g), ov = sigf(g_o);
        const float cn = fv * cst[gt][nt] + iv * gv;
        const float hn_new = ov * tanhf_(cn);
        const bool act = (t < mydeg[nt]);
        if (act) cst[gt][nt] = cn;
        const float hn = act ? hn_new : hprev[gt][nt];
        hprev[gt][nt] = hn;
        Hs[nxt][row * 128 + ((w ^ (row & 15)) * 8) + (col & 7)] = f2bf(hn);
      }
    }
    lgkm_barrier();   // single barrier: dbuf writes visible, reads done
  }

  // epilogue: Hs[maxdeg&1] (swizzled) -> hTB
  const bf16* Hf = Hs[maxdeg & 1];
  {
    const int row = tid >> 4, j = tid & 15;       // 64 rows x 16 octs, one per thread
    const int nd = nodes_s[row];
    if (nd >= 0) {
      const s16x8 v = ldfrag(Hf + row * 128 + ((j ^ (row & 15)) * 8));
      *(s16x8*)(hTB + (size_t)nd * HIDD + j * 8) = v;
    }
  }
}

// ------- SAGE: h1n = relu(feat@W_self + hT@W_neigh + b) * rsqrt(deg) -------
// feat read from the ORIGINAL float input (featB is dead/aliased by now);
// inline f2bf gives bit-identical frags to the old featB path.
__global__ __launch_bounds__(256) void sage_kernel(const float* __restrict__ featF,
                                                   const bf16* __restrict__ hTB,
                                                   const bf16* __restrict__ WsT,
                                                   const bf16* __restrict__ WnT,
                                                   const float* __restrict__ b_sage,
                                                   const int* __restrict__ deg,
                                                   bf16* __restrict__ h1n) {
  const int lane = threadIdx.x & 63, wave = threadIdx.x >> 6;
  const int l15 = lane & 15, quad = lane >> 4;
  const int nb = blockIdx.x * 64 + wave * 16;
  int arow = nb + l15; if (arow >= NN) arow = NN - 1;
  s16x8 Fa[4], Ha[4];
#pragma unroll
  for (int kt = 0; kt < 4; ++kt) {
    Fa[kt] = ldfrag_f32(featF + (size_t)arow * HIDD + kt * 32 + quad * 8);
    Ha[kt] = ldfrag(hTB + (size_t)arow * HIDD + kt * 32 + quad * 8);
  }
  int nodes[4]; float nrm[4];
#pragma unroll
  for (int r = 0; r < 4; ++r) {
    const int nd = nb + quad * 4 + r;
    nodes[r] = nd;
    nrm[r] = rsqrtf((float)deg[(nd < NN) ? nd : (NN - 1)]);
  }
  for (int ct = 0; ct < 8; ++ct) {
    const int col = ct * 16 + l15;
    f32x4 acc = {0.f, 0.f, 0.f, 0.f};
#pragma unroll
    for (int kt = 0; kt < 4; ++kt) {
      acc = MFMA16(Fa[kt], ldfrag(WsT + col * HIDD + kt * 32 + quad * 8), acc);
      acc = MFMA16(Ha[kt], ldfrag(WnT + col * HIDD + kt * 32 + quad * 8), acc);
    }
    const float bb = b_sage[col];
#pragma unroll
    for (int r = 0; r < 4; ++r)
      if (nodes[r] < NN) {
        const float v = fmaxf(acc[r] + bb, 0.f) * nrm[r];
        h1n[(size_t)nodes[r] * HIDD + col] = f2bf(v);
      }
  }
}

// ------- GraphConv aggregate: agg[n] = rsqrt(deg[n]) * sum_{t<deg} h1n[nbr[n,t]] -------
__global__ __launch_bounds__(256) void agg_kernel(const bf16* __restrict__ h1n,
                                                  const int* __restrict__ nbr_idx,
                                                  const int* __restrict__ deg,
                                                  bf16* __restrict__ aggB) {
  const int wave = threadIdx.x >> 6, lane = threadIdx.x & 63;
  const int node = blockIdx.x * 4 + wave;
  if (node >= NN) return;
  const int d = deg[node];
  const int idx_l = nbr_idx[node * MAXD + (lane & 15)];   // coalesced, broadcast via shfl
  const int c = lane * 2;
  float a0 = 0.f, a1 = 0.f;
  for (int t = 0; t < d; ++t) {
    const int nbr = __shfl(idx_l, t, 64);
    const __hip_bfloat162 v = *(const __hip_bfloat162*)(h1n + (size_t)nbr * HIDD + c);
    a0 += __bfloat162float(v.x);
    a1 += __bfloat162float(v.y);
  }
  const float nm = rsqrtf((float)d);
  aggB[(size_t)node * HIDD + c]     = f2bf(a0 * nm);
  aggB[(size_t)node * HIDD + c + 1] = f2bf(a1 * nm);
}

// ------- fused GraphConv GEMM + GRU: gout = gru(relu(agg @ W_gc + b_gc)) -------
__global__ __launch_bounds__(256) void gcgru_kernel(const bf16* __restrict__ aggB,
                                                    const bf16* __restrict__ WgT,
                                                    const float* __restrict__ b_gc,
                                                    const bf16* __restrict__ WgruB,
                                                    const float* __restrict__ bih,
                                                    const float* __restrict__ bhh,
                                                    float* __restrict__ gout) {
  __shared__ __align__(16) bf16 H2[64 * 136];     // h2 tile, padded pitch
  const int lane = threadIdx.x & 63, wave = threadIdx.x >> 6;
  const int l15 = lane & 15, quad = lane >> 4;
  const int nb = blockIdx.x * 64 + wave * 16;
  int arow = nb + l15; if (arow >= NN) arow = NN - 1;
  s16x8 A[4];
#pragma unroll
  for (int kt = 0; kt < 4; ++kt) A[kt] = ldfrag(aggB + (size_t)arow * HIDD + kt * 32 + quad * 8);
  // gc: h2 = relu(agg @ W_gc + b) -> LDS (C-layout -> row-major for gru A)
  for (int ct = 0; ct < 8; ++ct) {
    const int col = ct * 16 + l15;
    f32x4 acc = {0.f, 0.f, 0.f, 0.f};
#pragma unroll
    for (int kt = 0; kt < 4; ++kt)
      acc = MFMA16(A[kt], ldfrag(WgT + col * HIDD + kt * 32 + quad * 8), acc);
    const float bb = b_gc[col];
#pragma unroll
    for (int r = 0; r < 4; ++r)
      H2[(wave * 16 + quad * 4 + r) * 136 + col] = f2bf(fmaxf(acc[r] + bb, 0.f));
  }
  __syncthreads();
  // gru over rows wave*16 + l15
  s16x8 A2[4];
#pragma unroll
  for (int kt = 0; kt < 4; ++kt)
    A2[kt] = ldfrag(H2 + (wave * 16 + l15) * 136 + kt * 32 + quad * 8);
  f32x4 acc[6];
#pragma unroll
  for (int ct = 0; ct < 6; ++ct) {
    f32x4 a = {0.f, 0.f, 0.f, 0.f};
#pragma unroll
    for (int kt = 0; kt < 4; ++kt)
      a = MFMA16(A2[kt], ldfrag(WgruB + (ct * 16 + l15) * HIDD + kt * 32 + quad * 8), a);
    acc[ct] = a;
  }
#pragma unroll
  for (int u = 0; u < 2; ++u) {
    const int cu = 16 * u + l15;
    const float br = bih[cu] + bhh[cu];
    const float bz = bih[32 + cu] + bhh[32 + cu];
    const float bni = bih[64 + cu];
    const float bnh = bhh[64 + cu];
#pragma unroll
    for (int r = 0; r < 4; ++r) {
      const int node = nb + quad * 4 + r;
      if (node < NN) {
        const float rv = sigf(acc[u][r] + br);
        const float zv = sigf(acc[2 + u][r] + bz);
        const float nv = tanhf_(acc[4 + u][r] + bni + rv * bnh);
        gout[(size_t)node * GRUH + cu] = (1.f - zv) * nv;
      }
    }
  }
}

// ------- two-phase per-graph mean pool + classifier -------
#define POOL_CHUNK 512
__global__ __launch_bounds__(256) void pool_partial_kernel(const float* __restrict__ gout,
                                                           const int* __restrict__ gids,
                                                           float* __restrict__ sums,
                                                           float* __restrict__ cnts) {
  __shared__ float ls[NGRAPH * GRUH];
  __shared__ float lc[NGRAPH];
  const int tid = threadIdx.x;
  for (int i = tid; i < NGRAPH * GRUH; i += 256) ls[i] = 0.f;
  if (tid < NGRAPH) lc[tid] = 0.f;
  __syncthreads();

  const int wave = tid >> 6, lane = tid & 63;
  const int c = lane & 31, half = lane >> 5;
  const int base = blockIdx.x * POOL_CHUNK + wave * (POOL_CHUNK / 8);

  float accv = 0.f, ccnt = 0.f;
  int curg = -1;
  for (int it = 0; it < POOL_CHUNK / 16; ++it) {
    const int n = base + it * 2 + half;
    if (n < NN) {
      const int g = gids[n];
      const float v = gout[(size_t)n * GRUH + c];
      if (g != curg) {
        if (curg >= 0) {
          atomicAdd(&ls[curg * GRUH + c], accv);
          if (c == 0) atomicAdd(&lc[curg], ccnt);
        }
        curg = g; accv = 0.f; ccnt = 0.f;
      }
      accv += v; ccnt += 1.f;
    }
  }
  if (curg >= 0) {
    atomicAdd(&ls[curg * GRUH + c], accv);
    if (c == 0) atomicAdd(&lc[curg], ccnt);
  }
  __syncthreads();
  for (int i = tid; i < NGRAPH * GRUH; i += 256)
    if (ls[i] != 0.f) atomicAdd(&sums[i], ls[i]);
  if (tid < NGRAPH && lc[tid] != 0.f) atomicAdd(&cnts[tid], lc[tid]);
}

__global__ __launch_bounds__(256) void pool_final_kernel(const float* __restrict__ sums,
                                                         const float* __restrict__ cnts,
                                                         const float* __restrict__ Wcls,
                                                         const float* __restrict__ bcls,
                                                         float* __restrict__ out) {
  const int idx = blockIdx.x * blockDim.x + threadIdx.x;
  if (idx >= NGRAPH * NCLSS) return;
  const int g = idx / NCLSS, k = idx % NCLSS;
  const float inv = 1.0f / cnts[g];
  float acc = bcls[k];
#pragma unroll
  for (int cc = 0; cc < GRUH; ++cc)
    acc += sums[g * GRUH + cc] * inv * Wcls[cc * NCLSS + k];
  out[idx] = acc;
}

extern "C" void kernel_launch(void* const* d_in, const int* in_sizes, int n_in,
                              void* d_out, int out_size, void* d_ws, size_t ws_size,
                              hipStream_t stream) {
  const float* feature  = (const float*)d_in[0];
  const int*   nbr_idx  = (const int*)d_in[1];
  const int*   deg      = (const int*)d_in[2];
  const int*   gids     = (const int*)d_in[3];
  const float* lstm_Wih = (const float*)d_in[4];
  const float* lstm_Whh = (const float*)d_in[5];
  const float* lstm_bih = (const float*)d_in[6];
  const float* lstm_bhh = (const float*)d_in[7];
  const float* W_self   = (const float*)d_in[8];
  const float* W_neigh  = (const float*)d_in[9];
  const float* b_sage   = (const float*)d_in[10];
  const float* W_gc     = (const float*)d_in[11];
  const float* b_gc     = (const float*)d_in[12];
  const float* Wih_gru  = (const float*)d_in[13];
  const float* bih_gru  = (const float*)d_in[14];
  const float* bhh_gru  = (const float*)d_in[15];
  const float* W_cls    = (const float*)d_in[16];
  const float* b_cls    = (const float*)d_in[17];

  // workspace: peak 64.8 MB (within the 65.4 MB proven bound).
  // Timeline aliases: featB dead after ggemm -> hTB/gout at 0;
  // Gp dead after lstm -> h1nB/aggB inside its region.
  char* ws = (char*)d_ws;
  bf16*  featB = (bf16*)(ws + 0);           // [NN,128] 12.8MB (dead after ggemm)
  bf16*  hTB   = (bf16*)(ws + 0);           // alias featB (lstm out, sage in)
  float* gout  = (float*)(ws + 0);          // alias hTB (gcgru out, 6.4MB)
  bf16*  Gp    = (bf16*)(ws + 12800000);    // [NN,512] 51.2MB (dead after lstm)
  bf16*  h1nB  = (bf16*)(ws + 12800000);    // alias Gp[0:12.8M] (sage out, agg in)
  bf16*  aggB  = (bf16*)(ws + 25600000);    // alias Gp[12.8:25.6M] (agg out, gcgru in)
  const size_t wo = 64000000;
  bf16*  WihB  = (bf16*)(ws + wo);
  bf16*  WhhB  = (bf16*)(ws + wo + 131072);
  bf16*  WsT   = (bf16*)(ws + wo + 262144);
  bf16*  WnT   = (bf16*)(ws + wo + 294912);
  bf16*  WgT   = (bf16*)(ws + wo + 327680);
  bf16*  WgruB = (bf16*)(ws + wo + 360448);
  float* biasS = (float*)(ws + wo + 385024);
  int*   perm  = (int*)(ws + 64500000);
  int*   hist  = (int*)(ws + 64800000);     // [17]
  int*   resv  = hist + 17;                 // [17]
  float* psums = (float*)(ws + 64801216);   // [50][32]
  float* pcnts = psums + NGRAPH * GRUH;     // [50]

  prep_kernel<<<3072, 256, 0, stream>>>(feature, lstm_Wih, lstm_Whh, lstm_bih, lstm_bhh,
                                        W_self, W_neigh, W_gc, Wih_gru,
                                        featB, WihB, WhhB, WsT, WnT, WgT, WgruB, biasS);
  hipMemsetAsync(hist, 0, 34 * sizeof(int), stream);
  hipMemsetAsync(psums, 0, (NGRAPH * GRUH + NGRAPH) * sizeof(float), stream);
  hist_kernel<<<196, 256, 0, stream>>>(deg, hist);
  scatter_kernel<<<196, 256, 0, stream>>>(deg, hist, resv, perm);
  ggemm_kernel<<<782, 256, 0, stream>>>(featB, WihB, biasS, Gp);
  lstm_kernel<<<782, 1024, 0, stream>>>(Gp, WhhB, nbr_idx, deg, perm, hTB);
  sage_kernel<<<782, 256, 0, stream>>>(feature, hTB, WsT, WnT, b_sage, deg, h1nB);
  agg_kernel<<<12500, 256, 0, stream>>>(h1nB, nbr_idx, deg, aggB);
  gcgru_kernel<<<782, 256, 0, stream>>>(aggB, WgT, b_gc, WgruB, bih_gru, bhh_gru, gout);
  pool_partial_kernel<<<(NN + POOL_CHUNK - 1) / POOL_CHUNK, 256, 0, stream>>>(gout, gids, psums, pcnts);
  pool_final_kernel<<<2, 256, 0, stream>>>(psums, pcnts, W_cls, b_cls, (float*)d_out);
}